// Round 4
// baseline (226.246 us; speedup 1.0000x reference)
//
#include <hip/hip_runtime.h>
#include <stdint.h>

#define D_MODEL 1024
#define S_LEN   2048
#define BATCH   2
#define NHEAD   16
#define DHEAD   64
#define NTOK    (BATCH * S_LEN)   // 4096

typedef unsigned short u16;
typedef __attribute__((ext_vector_type(8))) short bf16x8;
typedef __attribute__((ext_vector_type(4))) float f32x4;
typedef __attribute__((ext_vector_type(16))) float f32x16;
typedef __attribute__((ext_vector_type(2))) unsigned int u32x2;

__device__ __forceinline__ unsigned pack2bf(float lo, float hi) {
    unsigned a = __float_as_uint(lo) + 0x8000u;
    unsigned b = __float_as_uint(hi) + 0x8000u;
    return __builtin_amdgcn_perm(b, a, 0x07060302u);  // lo16=bf16(lo), hi16=bf16(hi)
}
__device__ __forceinline__ u16 f2bf1(float f) {
    return (u16)((__float_as_uint(f) + 0x8000u) >> 16);
}

#define GAS(p) ((const __attribute__((address_space(1))) void*)(p))
#define LAS(p) ((__attribute__((address_space(3))) void*)(p))
// chunk-XOR swizzled flat [rows][64] bf16 tile: u16 index of (row, chunk-col c)
#define SWZ8(row, c) (((((row) << 3) | ((c) ^ ((row) & 7)))) << 3)

// ---------------------------------------------------------------------------
// convert: fp32 -> bf16 for Q,K,V (4M each) and Wq,Wk,Wv,Wo (1M each).
// ---------------------------------------------------------------------------
__global__ __launch_bounds__(256) void convert_kernel(
    const float* __restrict__ Q, const float* __restrict__ K, const float* __restrict__ V,
    const float* __restrict__ Wq, const float* __restrict__ Wk,
    const float* __restrict__ Wv, const float* __restrict__ Wo,
    u16* __restrict__ Qb, u16* __restrict__ Kb, u16* __restrict__ Vb,
    u16* __restrict__ Wqb, u16* __restrict__ Wkb, u16* __restrict__ Wvb, u16* __restrict__ Wob)
{
    const size_t SEG = 262144;  // float4 per 1M-float quarter
    size_t start = (size_t)blockIdx.x * 4096;
    int s = (int)(start / SEG);
    const float* src; u16* dst; size_t seg0;
    if (s < 4)       { src = Q;  dst = Qb;  seg0 = 0; }
    else if (s < 8)  { src = K;  dst = Kb;  seg0 = 4 * SEG; }
    else if (s < 12) { src = V;  dst = Vb;  seg0 = 8 * SEG; }
    else if (s == 12){ src = Wq; dst = Wqb; seg0 = 12 * SEG; }
    else if (s == 13){ src = Wk; dst = Wkb; seg0 = 13 * SEG; }
    else if (s == 14){ src = Wv; dst = Wvb; seg0 = 14 * SEG; }
    else             { src = Wo; dst = Wob; seg0 = 15 * SEG; }
    size_t off = start - seg0 + threadIdx.x;
    const float4* s4 = (const float4*)src;
    #pragma unroll
    for (int k = 0; k < 16; ++k) {
        float4 x = s4[off + (size_t)k * 256];
        u32x2 p = (u32x2){pack2bf(x.x, x.y), pack2bf(x.z, x.w)};
        *(u32x2*)(dst + (off + (size_t)k * 256) * 4) = p;
    }
}

// ---------------------------------------------------------------------------
// proj: all three projections in ONE launch. 256x256 tile, BK=64, 8 waves
// (2M x 4N), mfma_f32_32x32x16_bf16, double-buffered LDS (128 KB).
// R4: each K-tile is split into 4 barrier-paired QUADRANT PHASES
// (12 ds_read_b128 -> s_barrier -> lgkmcnt(0) -> 8 MFMA -> s_barrier).
// Next tile's 8 global_load_lds issue at phase 0; the confirming vmcnt(0)
// sits at phase 3 -> the drain overlaps ~3 phases of MFMA instead of
// blocking every wave at the tile boundary (T3-lite per m196/m218: the
// fine ds_read || G-load || MFMA interleave is the lever, not pipe depth).
// Race-safety: stage at (t,p0) writes the buffer whose last reads finished
// before barrier#2 of (t-1,p3); reads at (t,p0) are covered by the
// vmcnt(0)+barrier at (t-1,p3).
// XCD-chunked bijective swizzle (192 blocks = 24/XCD).
// Operand-swapped: A = W (m = dout), B = X (n = token).
//  z=0: qw[tok][dm] = (Qb@Wq^T + bq) * 0.125*log2(e)
//  z=1: kw[tok][dm] =  Kb@Wk^T + bk
//  z=2: vtw[dout][tok] = Wv@Vb^T + bv   (kv-contiguous rows for attention)
// ---------------------------------------------------------------------------
__global__ __launch_bounds__(512, 2) void proj_kernel(
    const u16* __restrict__ Qb, const u16* __restrict__ Kb, const u16* __restrict__ Vb,
    const u16* __restrict__ Wqb, const u16* __restrict__ Wkb, const u16* __restrict__ Wvb,
    const float* __restrict__ bq, const float* __restrict__ bk, const float* __restrict__ bv,
    u16* __restrict__ qw, u16* __restrict__ kw, u16* __restrict__ vtw)
{
    // 192 blocks total; bid%8 round-robins XCDs -> chunk 24 consecutive works/XCD
    const int bid = blockIdx.x;
    const int wid = (bid & 7) * 24 + (bid >> 3);
    const int z = wid >> 6;          // 0..2
    const int r = wid & 63;          // 0..63
    const int nbase = (r >> 2) * 256;   // token   (16 n-tiles)
    const int mbase = (r & 3) * 256;    // dout    (4 m-tiles)

    const u16* Ag = (z == 0) ? Wqb : (z == 1) ? Wkb : Wvb;   // [dout][din]
    const u16* Bg = (z == 0) ? Qb  : (z == 1) ? Kb  : Vb;    // [tok][din]
    const float* bias = (z == 0) ? bq : (z == 1) ? bk : bv;  // indexed by dout

    const int tid = threadIdx.x, lane = tid & 63, wave = tid >> 6;
    const int l31 = lane & 31, hh = lane >> 5;
    const int wm = wave >> 2;        // 0..1  -> 128 dout rows
    const int wn = wave & 3;         // 0..3  -> 64 tokens

    // LDS: A[2][256*64] at 0, B[2][256*64] at 32768 (u16 units). 128 KB total.
    __shared__ __align__(16) u16 smem[65536];

    // staging: 32 segments of 1 KB per matrix; wave w owns segs w*4..w*4+3.
    // chunkpos = seg*64 + lane; row = chunkpos>>3; chunk-col = (chunkpos&7)^(row&7)
    size_t aoff[4], boff[4];
    #pragma unroll
    for (int c = 0; c < 4; ++c) {
        int p = (wave * 4 + c) * 64 + lane;
        int row = p >> 3;
        int cg  = (p & 7) ^ (row & 7);
        aoff[c] = (size_t)(mbase + row) * D_MODEL + cg * 8;
        boff[c] = (size_t)(nbase + row) * D_MODEL + cg * 8;
    }

#define STAGE(buf, kc)                                                              \
    do {                                                                            \
        _Pragma("unroll")                                                           \
        for (int c = 0; c < 4; ++c) {                                               \
            __builtin_amdgcn_global_load_lds(GAS(Ag + aoff[c] + (kc)),              \
                LAS(smem + (buf) * 16384 + (wave * 4 + c) * 512), 16, 0, 0);        \
            __builtin_amdgcn_global_load_lds(GAS(Bg + boff[c] + (kc)),              \
                LAS(smem + 32768 + (buf) * 16384 + (wave * 4 + c) * 512), 16, 0, 0);\
        }                                                                           \
    } while (0)

    STAGE(0, 0);

    f32x16 acc[4][2];
    #pragma unroll
    for (int mt = 0; mt < 4; ++mt)
        #pragma unroll
        for (int nt = 0; nt < 2; ++nt)
            #pragma unroll
            for (int q = 0; q < 16; ++q) acc[mt][nt][q] = 0.f;

    asm volatile("s_waitcnt vmcnt(0)" ::: "memory");
    __builtin_amdgcn_s_barrier();
    asm volatile("" ::: "memory");

    for (int t = 0; t < 16; ++t) {
        const int cur = t & 1;
        const u16* Ab = smem + cur * 16384;
        const u16* Bb = smem + 32768 + cur * 16384;
        #pragma unroll
        for (int q = 0; q < 4; ++q) {
            const int qm = q >> 1, qn = q & 1;
            // stage next tile's loads at phase 0 (writes buf cur^1, whose
            // last reads completed before the previous barrier)
            if (q == 0 && t < 15) STAGE(cur ^ 1, (t + 1) * 64);
            // quadrant frags: 2 M-tiles x 4 kk (A), 1 N-tile x 4 kk (B)
            bf16x8 af0[4], af1[4], bfr[4];
            #pragma unroll
            for (int kk = 0; kk < 4; ++kk) {
                af0[kk] = *(const bf16x8*)&Ab[SWZ8(wm * 128 + (2 * qm) * 32 + l31, kk * 2 + hh)];
                af1[kk] = *(const bf16x8*)&Ab[SWZ8(wm * 128 + (2 * qm + 1) * 32 + l31, kk * 2 + hh)];
                bfr[kk] = *(const bf16x8*)&Bb[SWZ8(wn * 64 + qn * 32 + l31, kk * 2 + hh)];
            }
            // confirm next tile's stage at the LAST phase (3 phases of
            // MFMA have covered the flight time); never earlier.
            if (q == 3 && t < 15) asm volatile("s_waitcnt vmcnt(0)" ::: "memory");
            asm volatile("" ::: "memory");
            __builtin_amdgcn_s_barrier();
            asm volatile("s_waitcnt lgkmcnt(0)" ::: "memory");
            __builtin_amdgcn_s_setprio(1);
            #pragma unroll
            for (int kk = 0; kk < 4; ++kk) {
                acc[2 * qm][qn]     = __builtin_amdgcn_mfma_f32_32x32x16_bf16(af0[kk], bfr[kk], acc[2 * qm][qn], 0, 0, 0);
                acc[2 * qm + 1][qn] = __builtin_amdgcn_mfma_f32_32x32x16_bf16(af1[kk], bfr[kk], acc[2 * qm + 1][qn], 0, 0, 0);
            }
            __builtin_amdgcn_s_setprio(0);
            asm volatile("" ::: "memory");
            __builtin_amdgcn_s_barrier();
        }
    }
#undef STAGE

    // C layout (32x32x16): col(token) = lane&31, row(dout) = (reg&3)+8*(reg>>2)+4*hh
    if (z < 2) {
        u16* Y = z ? kw : qw;
        const float scale = z ? 1.0f : 0.18033688011112042f;  // 0.125*log2(e)
        #pragma unroll
        for (int mt = 0; mt < 4; ++mt)
            #pragma unroll
            for (int nt = 0; nt < 2; ++nt) {
                const int tok = nbase + wn * 64 + nt * 32 + l31;
                u16* yrow = Y + (size_t)tok * D_MODEL;
                #pragma unroll
                for (int g = 0; g < 4; ++g) {
                    const int d0 = mbase + wm * 128 + mt * 32 + 8 * g + 4 * hh;
                    float4 b4 = *(const float4*)&bias[d0];
                    float v0 = (acc[mt][nt][4 * g + 0] + b4.x) * scale;
                    float v1 = (acc[mt][nt][4 * g + 1] + b4.y) * scale;
                    float v2 = (acc[mt][nt][4 * g + 2] + b4.z) * scale;
                    float v3 = (acc[mt][nt][4 * g + 3] + b4.w) * scale;
                    *(u32x2*)(yrow + d0) = (u32x2){pack2bf(v0, v1), pack2bf(v2, v3)};
                }
            }
    } else {
        #pragma unroll
        for (int mt = 0; mt < 4; ++mt)
            #pragma unroll
            for (int nt = 0; nt < 2; ++nt) {
                const int tok = nbase + wn * 64 + nt * 32 + l31;
                #pragma unroll
                for (int g = 0; g < 4; ++g) {
                    const int d0 = mbase + wm * 128 + mt * 32 + 8 * g + 4 * hh;
                    #pragma unroll
                    for (int q = 0; q < 4; ++q)
                        vtw[(size_t)(d0 + q) * NTOK + tok] =
                            f2bf1(acc[mt][nt][4 * g + q] + bias[d0 + q]);
                }
            }
    }
}

// ---------------------------------------------------------------------------
// Flash attention, 512-thread blocks: 8 waves = 4 q-tiles(32q) x 2 kv-halves.
// Each wave: QK (A=K half, B=Q tile) 4 MFMA -> exp2 -> permlane32_swap ->
// PV (A=V^T, B=P^T) 4 MFMA. P packing via v_cvt_pk_bf16_f32 (1 instr/pair);
// cross-half exchange via v_permlane32_swap_b32 (VALU crossbar, no LDS —
// one swap yields BOTH P-frag words: a'={a.lo,b.lo}, b'={a.hi,b.hi}).
// s_setprio(1) around MFMA clusters (T5). Fixed-max exp2 softmax.
// ---------------------------------------------------------------------------
__global__ __launch_bounds__(512, 4) void attn_kernel(
    const u16* __restrict__ qw, const u16* __restrict__ kw,
    const u16* __restrict__ vtw, u16* __restrict__ aw)
{
    const int qbase = blockIdx.x * 128;
    const int h = blockIdx.y, b = blockIdx.z;
    const int tid = threadIdx.x, lane = tid & 63, wave = tid >> 6;
    const int wq = wave & 3;        // q-tile (32 q rows)
    const int wk = wave >> 2;       // kv half (32 kv rows of the 64-tile)
    const int l31 = lane & 31;
    const int hh  = lane >> 5;
    const int colbase = h * DHEAD;
    const size_t qrow0 = (size_t)b * S_LEN + qbase;

    // smem layout (u16 offsets): Ks[buf] at buf*4096, Vs[buf] at 8192+buf*4096;
    // after the kv loop the same region is reused as Ored [4][32][68] f32 +
    // Lred [4][32] f32 at u16 offset 17408. Total 17664 u16 = 35328 B.
    __shared__ __align__(16) u16 smem[17664];
    #define KS_OFF(buf) ((buf) * 4096)
    #define VS_OFF(buf) (8192 + (buf) * 4096)

    // staging: one chunk per thread (512 chunks per 64x64 tile)
    const int srow = tid >> 3;
    const int scg  = (tid & 7) ^ (srow & 7);
    const size_t ksrc = ((size_t)b * S_LEN + srow) * D_MODEL + colbase + scg * 8;
    const size_t vsrc = (size_t)(colbase + srow) * NTOK + (size_t)b * S_LEN + scg * 8;

    #define STAGE_KV(buf, kv0)                                                         \
        do {                                                                           \
            __builtin_amdgcn_global_load_lds(GAS(kw + ksrc + (size_t)(kv0) * D_MODEL), \
                                             LAS(smem + KS_OFF(buf) + wave * 512), 16, 0, 0); \
            __builtin_amdgcn_global_load_lds(GAS(vtw + vsrc + (kv0)),                  \
                                             LAS(smem + VS_OFF(buf) + wave * 512), 16, 0, 0); \
        } while (0)

    // Q B-frags, register-resident: B[k=d=16s+8hh+j][n=q=l31]
    bf16x8 qf[4];
    {
        const u16* qptr = qw + (qrow0 + wq * 32 + l31) * D_MODEL + colbase + hh * 8;
        #pragma unroll
        for (int s = 0; s < 4; ++s) qf[s] = *(const bf16x8*)(qptr + s * 16);
    }

    STAGE_KV(0, 0);

    f32x16 o[2];
    #pragma unroll
    for (int dt = 0; dt < 2; ++dt)
        #pragma unroll
        for (int r = 0; r < 16; ++r) o[dt][r] = 0.f;
    float l = 0.f;

    __syncthreads();

    for (int t = 0; t < S_LEN / 64; ++t) {
        const int cur = t & 1;
        if (t + 1 < S_LEN / 64) STAGE_KV(!cur, (t + 1) * 64);   // prefetch in flight

        // S^T (this wave's 32 kv rows x 32 q cols), C init -12 (exp2 headroom)
        f32x16 sc;
        #pragma unroll
        for (int r = 0; r < 16; ++r) sc[r] = -12.f;
        __builtin_amdgcn_s_setprio(1);
        #pragma unroll
        for (int s = 0; s < 4; ++s) {
            bf16x8 kf = *(const bf16x8*)&smem[KS_OFF(cur) + SWZ8(wk * 32 + l31, s * 2 + hh)];
            sc = __builtin_amdgcn_mfma_f32_32x32x16_bf16(kf, qf[s], sc, 0, 0, 0);
        }
        __builtin_amdgcn_s_setprio(0);

        // p = exp2(s); x[g] covers kv_local = 8g + 4hh + {0..3}
        // v_cvt_pk_bf16_f32: 1 instr packs 2 f32 -> 2 bf16 (no builtin; asm)
        unsigned x[4][2];
        #pragma unroll
        for (int g = 0; g < 4; ++g) {
            float p0 = __builtin_amdgcn_exp2f(sc[4 * g + 0]);
            float p1 = __builtin_amdgcn_exp2f(sc[4 * g + 1]);
            float p2 = __builtin_amdgcn_exp2f(sc[4 * g + 2]);
            float p3 = __builtin_amdgcn_exp2f(sc[4 * g + 3]);
            l += (p0 + p1) + (p2 + p3);
            asm("v_cvt_pk_bf16_f32 %0, %1, %2" : "=v"(x[g][0]) : "v"(p0), "v"(p1));
            asm("v_cvt_pk_bf16_f32 %0, %1, %2" : "=v"(x[g][1]) : "v"(p2), "v"(p3));
        }

        // PV: B-frag(sp) covers kv_local = 16sp + 8hh + j.
        // pf.u[w] needs {lo lanes: x[ge][w&1].row0, hi lanes: x[go][w&1].row0}
        // (w<2) and row1 halves (w>=2) — exactly the two outputs of one
        // v_permlane32_swap_b32 (swaps row1(a) <-> row0(b)).
        #pragma unroll
        for (int sp = 0; sp < 2; ++sp) {
            unsigned a0 = x[2 * sp][0], b0 = x[2 * sp + 1][0];
            unsigned a1 = x[2 * sp][1], b1 = x[2 * sp + 1][1];
            asm("v_permlane32_swap_b32 %0, %1" : "+v"(a0), "+v"(b0));
            asm("v_permlane32_swap_b32 %0, %1" : "+v"(a1), "+v"(b1));
            union { unsigned u[4]; bf16x8 v; } pf;
            pf.u[0] = a0; pf.u[1] = a1; pf.u[2] = b0; pf.u[3] = b1;
            __builtin_amdgcn_s_setprio(1);
            #pragma unroll
            for (int dt = 0; dt < 2; ++dt) {
                bf16x8 vf = *(const bf16x8*)&smem[VS_OFF(cur) + SWZ8(dt * 32 + l31, wk * 4 + sp * 2 + hh)];
                o[dt] = __builtin_amdgcn_mfma_f32_32x32x16_bf16(vf, pf.v, o[dt], 0, 0, 0);
            }
            __builtin_amdgcn_s_setprio(0);
        }

        __syncthreads();   // drains prefetch + protects both staging buffers
    }

    // merge lane halves of l (each covers complementary kv groups)
    l += __shfl_xor(l, 32);

    // cross kv-half reduction through LDS (staging region is dead now)
    float* Ored = (float*)smem;                   // [4 qt][32 q][68] f32
    float* Lred = (float*)(smem + 17408);         // [4 qt][32 q] f32
    float* op = Ored + ((size_t)wq * 32 + l31) * 68;
    if (wk == 1) {
        #pragma unroll
        for (int dt = 0; dt < 2; ++dt)
            #pragma unroll
            for (int g = 0; g < 4; ++g)
                *(f32x4*)(op + dt * 32 + 8 * g + 4 * hh) =
                    (f32x4){o[dt][4 * g + 0], o[dt][4 * g + 1], o[dt][4 * g + 2], o[dt][4 * g + 3]};
        if (hh == 0) Lred[wq * 32 + l31] = l;
    }
    __syncthreads();
    if (wk == 0) {
        l += Lred[wq * 32 + l31];
        float inv = 1.0f / l;
        size_t orow = (qrow0 + wq * 32 + l31) * D_MODEL + colbase;
        #pragma unroll
        for (int dt = 0; dt < 2; ++dt)
            #pragma unroll
            for (int g = 0; g < 4; ++g) {
                f32x4 add = *(const f32x4*)(op + dt * 32 + 8 * g + 4 * hh);
                float v0 = (o[dt][4 * g + 0] + add[0]) * inv;
                float v1 = (o[dt][4 * g + 1] + add[1]) * inv;
                float v2 = (o[dt][4 * g + 2] + add[2]) * inv;
                float v3 = (o[dt][4 * g + 3] + add[3]) * inv;
                *(u32x2*)(aw + orow + dt * 32 + 8 * g + 4 * hh) =
                    (u32x2){pack2bf(v0, v1), pack2bf(v2, v3)};
            }
    }
    #undef STAGE_KV
    #undef KS_OFF
    #undef VS_OFF
}

// ---------------------------------------------------------------------------
// outproj: out[tok][dm] = aw @ Wo^T + bo (fp32 out). Operand-swapped
// (A=Wo m=dout, B=aw n=tok) -> float4 epilogue stores. Tile 128(dout)x64(tok).
// ---------------------------------------------------------------------------
__global__ __launch_bounds__(256) void outproj_kernel(
    const u16* __restrict__ aw, const u16* __restrict__ Wob,
    const float* __restrict__ bo, float* __restrict__ out)
{
    const int nbase = blockIdx.x * 64;    // token
    const int mbase = blockIdx.y * 128;   // dout
    const int tid = threadIdx.x, lane = tid & 63, wave = tid >> 6;
    const int m16 = lane & 15, quad = lane >> 4;
    const int wm = wave >> 1, wn = wave & 1;

    __shared__ __align__(16) u16 As[128 * 64];  // Wo tile
    __shared__ __align__(16) u16 Bs[64 * 64];   // aw tile

    int arow[4], acg[4], brow[2], bcg[2];
    #pragma unroll
    for (int c = 0; c < 4; ++c) {
        int p = (wave * 4 + c) * 64 + lane;
        arow[c] = p >> 3; acg[c] = (p & 7) ^ (arow[c] & 7);
    }
    #pragma unroll
    for (int c = 0; c < 2; ++c) {
        int p = (wave * 2 + c) * 64 + lane;
        brow[c] = p >> 3; bcg[c] = (p & 7) ^ (brow[c] & 7);
    }

    f32x4 acc[4][2];
    #pragma unroll
    for (int mt = 0; mt < 4; ++mt)
        #pragma unroll
        for (int nt = 0; nt < 2; ++nt) acc[mt][nt] = (f32x4){0.f, 0.f, 0.f, 0.f};

    for (int kc = 0; kc < D_MODEL; kc += 64) {
        #pragma unroll
        for (int c = 0; c < 4; ++c)
            __builtin_amdgcn_global_load_lds(
                GAS(Wob + (size_t)(mbase + arow[c]) * D_MODEL + kc + acg[c] * 8),
                LAS(As + (wave * 4 + c) * 512), 16, 0, 0);
        #pragma unroll
        for (int c = 0; c < 2; ++c)
            __builtin_amdgcn_global_load_lds(
                GAS(aw + (size_t)(nbase + brow[c]) * D_MODEL + kc + bcg[c] * 8),
                LAS(Bs + (wave * 2 + c) * 512), 16, 0, 0);
        __syncthreads();
        #pragma unroll
        for (int half = 0; half < 2; ++half) {
            bf16x8 af[4], bfr[2];
            #pragma unroll
            for (int mt = 0; mt < 4; ++mt)
                af[mt] = *(const bf16x8*)&As[SWZ8(wm * 64 + mt * 16 + m16, quad + 4 * half)];
            #pragma unroll
            for (int nt = 0; nt < 2; ++nt)
                bfr[nt] = *(const bf16x8*)&Bs[SWZ8(wn * 32 + nt * 16 + m16, quad + 4 * half)];
            #pragma unroll
            for (int mt = 0; mt < 4; ++mt)
                #pragma unroll
                for (int nt = 0; nt < 2; ++nt)
                    acc[mt][nt] = __builtin_amdgcn_mfma_f32_16x16x32_bf16(af[mt], bfr[nt], acc[mt][nt], 0, 0, 0);
        }
        __syncthreads();
    }

    #pragma unroll
    for (int mt = 0; mt < 4; ++mt) {
        int d0 = mbase + wm * 64 + mt * 16 + quad * 4;
        float4 b4 = *(const float4*)&bo[d0];
        #pragma unroll
        for (int nt = 0; nt < 2; ++nt) {
            int tok = nbase + wn * 32 + nt * 16 + m16;
            float4 st;
            st.x = acc[mt][nt][0] + b4.x;
            st.y = acc[mt][nt][1] + b4.y;
            st.z = acc[mt][nt][2] + b4.z;
            st.w = acc[mt][nt][3] + b4.w;
            *(float4*)(out + (size_t)tok * D_MODEL + d0) = st;
        }
    }
}

extern "C" void kernel_launch(void* const* d_in, const int* in_sizes, int n_in,
                              void* d_out, int out_size, void* d_ws, size_t ws_size,
                              hipStream_t stream) {
    const float* Q  = (const float*)d_in[0];
    const float* K  = (const float*)d_in[1];
    const float* V  = (const float*)d_in[2];
    const float* Wq = (const float*)d_in[3];
    const float* bq = (const float*)d_in[4];
    const float* Wk = (const float*)d_in[5];
    const float* bk = (const float*)d_in[6];
    const float* Wv = (const float*)d_in[7];
    const float* bv = (const float*)d_in[8];
    const float* Wo = (const float*)d_in[9];
    const float* bo = (const float*)d_in[10];

    const size_t NT = (size_t)NTOK * D_MODEL;    // 4M
    const size_t WN = (size_t)D_MODEL * D_MODEL; // 1M
    u16* base = (u16*)d_ws;                      // 28M u16 = 56 MB total
    u16* qw  = base;
    u16* kw  = base + NT;
    u16* vtw = base + 2 * NT;   // [1024 dout][4096 tok]
    u16* Qb  = base + 3 * NT;   // aliased by aww after proj
    u16* Kb  = base + 4 * NT;
    u16* Vb  = base + 5 * NT;
    u16* Wqb = base + 6 * NT;
    u16* Wkb = Wqb + WN;
    u16* Wvb = Wkb + WN;
    u16* Wob = Wvb + WN;
    u16* aww = Qb;              // Qb dead after proj

    convert_kernel<<<1024, 256, 0, stream>>>(Q, K, V, Wq, Wk, Wv, Wo,
                                             Qb, Kb, Vb, Wqb, Wkb, Wvb, Wob);
    proj_kernel<<<dim3(192), 512, 0, stream>>>(Qb, Kb, Vb, Wqb, Wkb, Wvb,
                                               bq, bk, bv, qw, kw, vtw);
    attn_kernel<<<dim3(S_LEN / 128, NHEAD, BATCH), 512, 0, stream>>>(qw, kw, vtw, aww);
    outproj_kernel<<<dim3(NTOK / 64, D_MODEL / 128), 256, 0, stream>>>(
        aww, Wob, bo, (float*)d_out);
}

// Round 5
// 212.262 us; speedup vs baseline: 1.0659x; 1.0659x over previous
//
#include <hip/hip_runtime.h>
#include <stdint.h>

#define D_MODEL 1024
#define S_LEN   2048
#define BATCH   2
#define NHEAD   16
#define DHEAD   64
#define NTOK    (BATCH * S_LEN)   // 4096

typedef unsigned short u16;
typedef __attribute__((ext_vector_type(8))) short bf16x8;
typedef __attribute__((ext_vector_type(4))) float f32x4;
typedef __attribute__((ext_vector_type(16))) float f32x16;
typedef __attribute__((ext_vector_type(2))) unsigned int u32x2;

__device__ __forceinline__ unsigned pack2bf(float lo, float hi) {
    unsigned a = __float_as_uint(lo) + 0x8000u;
    unsigned b = __float_as_uint(hi) + 0x8000u;
    return __builtin_amdgcn_perm(b, a, 0x07060302u);  // lo16=bf16(lo), hi16=bf16(hi)
}
__device__ __forceinline__ u16 f2bf1(float f) {
    return (u16)((__float_as_uint(f) + 0x8000u) >> 16);
}

#define GAS(p) ((const __attribute__((address_space(1))) void*)(p))
#define LAS(p) ((__attribute__((address_space(3))) void*)(p))
// chunk-XOR swizzled flat [rows][64] bf16 tile: u16 index of (row, chunk-col c)
#define SWZ8(row, c) (((((row) << 3) | ((c) ^ ((row) & 7)))) << 3)

// ---------------------------------------------------------------------------
// convert: fp32 -> bf16 for Q,K,V (4M each) and Wq,Wk,Wv,Wo (1M each).
// ---------------------------------------------------------------------------
__global__ __launch_bounds__(256) void convert_kernel(
    const float* __restrict__ Q, const float* __restrict__ K, const float* __restrict__ V,
    const float* __restrict__ Wq, const float* __restrict__ Wk,
    const float* __restrict__ Wv, const float* __restrict__ Wo,
    u16* __restrict__ Qb, u16* __restrict__ Kb, u16* __restrict__ Vb,
    u16* __restrict__ Wqb, u16* __restrict__ Wkb, u16* __restrict__ Wvb, u16* __restrict__ Wob)
{
    const size_t SEG = 262144;  // float4 per 1M-float quarter
    size_t start = (size_t)blockIdx.x * 4096;
    int s = (int)(start / SEG);
    const float* src; u16* dst; size_t seg0;
    if (s < 4)       { src = Q;  dst = Qb;  seg0 = 0; }
    else if (s < 8)  { src = K;  dst = Kb;  seg0 = 4 * SEG; }
    else if (s < 12) { src = V;  dst = Vb;  seg0 = 8 * SEG; }
    else if (s == 12){ src = Wq; dst = Wqb; seg0 = 12 * SEG; }
    else if (s == 13){ src = Wk; dst = Wkb; seg0 = 13 * SEG; }
    else if (s == 14){ src = Wv; dst = Wvb; seg0 = 14 * SEG; }
    else             { src = Wo; dst = Wob; seg0 = 15 * SEG; }
    size_t off = start - seg0 + threadIdx.x;
    const float4* s4 = (const float4*)src;
    #pragma unroll
    for (int k = 0; k < 16; ++k) {
        float4 x = s4[off + (size_t)k * 256];
        u32x2 p = (u32x2){pack2bf(x.x, x.y), pack2bf(x.z, x.w)};
        *(u32x2*)(dst + (off + (size_t)k * 256) * 4) = p;
    }
}

// ---------------------------------------------------------------------------
// proj: all three projections in ONE launch. 256x256 tile, BK=64, 8 waves
// (2M x 4N), mfma_f32_32x32x16_bf16, double-buffered LDS (128 KB) with one
// raw s_barrier + vmcnt(0) per K-tile; next tile's global_load_lds issued
// right after the barrier so loads fly across a full compute section.
// (R2 structure, measured 46.1 us — R3/R4 scheduling variants both
// regressed; at 1 block/CU this is the local optimum.)
// XCD-chunked bijective swizzle (192 blocks = 24/XCD).
// Operand-swapped: A = W (m = dout), B = X (n = token).
//  z=0: qw[tok][dm] = (Qb@Wq^T + bq) * 0.125*log2(e)
//  z=1: kw[tok][dm] =  Kb@Wk^T + bk
//  z=2: vtw[dout][tok] = Wv@Vb^T + bv   (kv-contiguous rows for attention)
// ---------------------------------------------------------------------------
__global__ __launch_bounds__(512, 2) void proj_kernel(
    const u16* __restrict__ Qb, const u16* __restrict__ Kb, const u16* __restrict__ Vb,
    const u16* __restrict__ Wqb, const u16* __restrict__ Wkb, const u16* __restrict__ Wvb,
    const float* __restrict__ bq, const float* __restrict__ bk, const float* __restrict__ bv,
    u16* __restrict__ qw, u16* __restrict__ kw, u16* __restrict__ vtw)
{
    // 192 blocks total; bid%8 round-robins XCDs -> chunk 24 consecutive works/XCD
    const int bid = blockIdx.x;
    const int wid = (bid & 7) * 24 + (bid >> 3);
    const int z = wid >> 6;          // 0..2
    const int r = wid & 63;          // 0..63
    const int nbase = (r >> 2) * 256;   // token   (16 n-tiles)
    const int mbase = (r & 3) * 256;    // dout    (4 m-tiles)

    const u16* Ag = (z == 0) ? Wqb : (z == 1) ? Wkb : Wvb;   // [dout][din]
    const u16* Bg = (z == 0) ? Qb  : (z == 1) ? Kb  : Vb;    // [tok][din]
    const float* bias = (z == 0) ? bq : (z == 1) ? bk : bv;  // indexed by dout

    const int tid = threadIdx.x, lane = tid & 63, wave = tid >> 6;
    const int l31 = lane & 31, hh = lane >> 5;
    const int wm = wave >> 2;        // 0..1  -> 128 dout rows
    const int wn = wave & 3;         // 0..3  -> 64 tokens

    // LDS: A[2][256*64] at 0, B[2][256*64] at 32768 (u16 units). 128 KB total.
    __shared__ __align__(16) u16 smem[65536];

    // staging: 32 segments of 1 KB per matrix; wave w owns segs w*4..w*4+3.
    // chunkpos = seg*64 + lane; row = chunkpos>>3; chunk-col = (chunkpos&7)^(row&7)
    size_t aoff[4], boff[4];
    #pragma unroll
    for (int c = 0; c < 4; ++c) {
        int p = (wave * 4 + c) * 64 + lane;
        int row = p >> 3;
        int cg  = (p & 7) ^ (row & 7);
        aoff[c] = (size_t)(mbase + row) * D_MODEL + cg * 8;
        boff[c] = (size_t)(nbase + row) * D_MODEL + cg * 8;
    }

#define STAGE(buf, kc)                                                              \
    do {                                                                            \
        _Pragma("unroll")                                                           \
        for (int c = 0; c < 4; ++c) {                                               \
            __builtin_amdgcn_global_load_lds(GAS(Ag + aoff[c] + (kc)),              \
                LAS(smem + (buf) * 16384 + (wave * 4 + c) * 512), 16, 0, 0);        \
            __builtin_amdgcn_global_load_lds(GAS(Bg + boff[c] + (kc)),              \
                LAS(smem + 32768 + (buf) * 16384 + (wave * 4 + c) * 512), 16, 0, 0);\
        }                                                                           \
    } while (0)

    STAGE(0, 0);

    f32x16 acc[4][2];
    #pragma unroll
    for (int mt = 0; mt < 4; ++mt)
        #pragma unroll
        for (int nt = 0; nt < 2; ++nt)
            #pragma unroll
            for (int q = 0; q < 16; ++q) acc[mt][nt][q] = 0.f;

    for (int t = 0; t < D_MODEL / 64; ++t) {
        const int cur = t & 1;
        // wait own stage loads of tile t (flew across previous compute section)
        asm volatile("s_waitcnt vmcnt(0) lgkmcnt(0)" ::: "memory");
        __builtin_amdgcn_s_barrier();
        asm volatile("" ::: "memory");
        if (t < D_MODEL / 64 - 1) STAGE(cur ^ 1, (t + 1) * 64);
        const u16* Ab = smem + cur * 16384;
        const u16* Bb = smem + 32768 + cur * 16384;
        #pragma unroll
        for (int kk = 0; kk < 4; ++kk) {
            bf16x8 af[4], bfr[2];
            #pragma unroll
            for (int mt = 0; mt < 4; ++mt)
                af[mt] = *(const bf16x8*)&Ab[SWZ8(wm * 128 + mt * 32 + l31, kk * 2 + hh)];
            #pragma unroll
            for (int nt = 0; nt < 2; ++nt)
                bfr[nt] = *(const bf16x8*)&Bb[SWZ8(wn * 64 + nt * 32 + l31, kk * 2 + hh)];
            #pragma unroll
            for (int mt = 0; mt < 4; ++mt)
                #pragma unroll
                for (int nt = 0; nt < 2; ++nt)
                    acc[mt][nt] = __builtin_amdgcn_mfma_f32_32x32x16_bf16(af[mt], bfr[nt], acc[mt][nt], 0, 0, 0);
        }
    }
#undef STAGE

    // C layout (32x32x16): col(token) = lane&31, row(dout) = (reg&3)+8*(reg>>2)+4*hh
    if (z < 2) {
        u16* Y = z ? kw : qw;
        const float scale = z ? 1.0f : 0.18033688011112042f;  // 0.125*log2(e)
        #pragma unroll
        for (int mt = 0; mt < 4; ++mt)
            #pragma unroll
            for (int nt = 0; nt < 2; ++nt) {
                const int tok = nbase + wn * 64 + nt * 32 + l31;
                u16* yrow = Y + (size_t)tok * D_MODEL;
                #pragma unroll
                for (int g = 0; g < 4; ++g) {
                    const int d0 = mbase + wm * 128 + mt * 32 + 8 * g + 4 * hh;
                    float4 b4 = *(const float4*)&bias[d0];
                    float v0 = (acc[mt][nt][4 * g + 0] + b4.x) * scale;
                    float v1 = (acc[mt][nt][4 * g + 1] + b4.y) * scale;
                    float v2 = (acc[mt][nt][4 * g + 2] + b4.z) * scale;
                    float v3 = (acc[mt][nt][4 * g + 3] + b4.w) * scale;
                    *(u32x2*)(yrow + d0) = (u32x2){pack2bf(v0, v1), pack2bf(v2, v3)};
                }
            }
    } else {
        #pragma unroll
        for (int mt = 0; mt < 4; ++mt)
            #pragma unroll
            for (int nt = 0; nt < 2; ++nt) {
                const int tok = nbase + wn * 64 + nt * 32 + l31;
                #pragma unroll
                for (int g = 0; g < 4; ++g) {
                    const int d0 = mbase + wm * 128 + mt * 32 + 8 * g + 4 * hh;
                    #pragma unroll
                    for (int q = 0; q < 4; ++q)
                        vtw[(size_t)(d0 + q) * NTOK + tok] =
                            f2bf1(acc[mt][nt][4 * g + q] + bias[d0 + q]);
                }
            }
    }
}

// ---------------------------------------------------------------------------
// Flash attention, 512-thread blocks: 8 waves = 4 q-tiles(32q) x 2 kv-halves.
// Each wave: QK (A=K half, B=Q tile) 4 MFMA -> exp2 -> permlane32_swap ->
// PV (A=V^T, B=P^T) 4 MFMA. P packing via v_cvt_pk_bf16_f32 (1 instr/pair);
// cross-half exchange via v_permlane32_swap_b32 (VALU crossbar, no LDS —
// one swap yields BOTH P-frag words: a'={a.lo,b.lo}, b'={a.hi,b.hi}).
// s_setprio(1) around MFMA clusters (T5). Fixed-max exp2 softmax.
// ---------------------------------------------------------------------------
__global__ __launch_bounds__(512, 4) void attn_kernel(
    const u16* __restrict__ qw, const u16* __restrict__ kw,
    const u16* __restrict__ vtw, u16* __restrict__ aw)
{
    const int qbase = blockIdx.x * 128;
    const int h = blockIdx.y, b = blockIdx.z;
    const int tid = threadIdx.x, lane = tid & 63, wave = tid >> 6;
    const int wq = wave & 3;        // q-tile (32 q rows)
    const int wk = wave >> 2;       // kv half (32 kv rows of the 64-tile)
    const int l31 = lane & 31;
    const int hh  = lane >> 5;
    const int colbase = h * DHEAD;
    const size_t qrow0 = (size_t)b * S_LEN + qbase;

    // smem layout (u16 offsets): Ks[buf] at buf*4096, Vs[buf] at 8192+buf*4096;
    // after the kv loop the same region is reused as Ored [4][32][68] f32 +
    // Lred [4][32] f32 at u16 offset 17408. Total 17664 u16 = 35328 B.
    __shared__ __align__(16) u16 smem[17664];
    #define KS_OFF(buf) ((buf) * 4096)
    #define VS_OFF(buf) (8192 + (buf) * 4096)

    // staging: one chunk per thread (512 chunks per 64x64 tile)
    const int srow = tid >> 3;
    const int scg  = (tid & 7) ^ (srow & 7);
    const size_t ksrc = ((size_t)b * S_LEN + srow) * D_MODEL + colbase + scg * 8;
    const size_t vsrc = (size_t)(colbase + srow) * NTOK + (size_t)b * S_LEN + scg * 8;

    #define STAGE_KV(buf, kv0)                                                         \
        do {                                                                           \
            __builtin_amdgcn_global_load_lds(GAS(kw + ksrc + (size_t)(kv0) * D_MODEL), \
                                             LAS(smem + KS_OFF(buf) + wave * 512), 16, 0, 0); \
            __builtin_amdgcn_global_load_lds(GAS(vtw + vsrc + (kv0)),                  \
                                             LAS(smem + VS_OFF(buf) + wave * 512), 16, 0, 0); \
        } while (0)

    // Q B-frags, register-resident: B[k=d=16s+8hh+j][n=q=l31]
    bf16x8 qf[4];
    {
        const u16* qptr = qw + (qrow0 + wq * 32 + l31) * D_MODEL + colbase + hh * 8;
        #pragma unroll
        for (int s = 0; s < 4; ++s) qf[s] = *(const bf16x8*)(qptr + s * 16);
    }

    STAGE_KV(0, 0);

    f32x16 o[2];
    #pragma unroll
    for (int dt = 0; dt < 2; ++dt)
        #pragma unroll
        for (int r = 0; r < 16; ++r) o[dt][r] = 0.f;
    float l = 0.f;

    __syncthreads();

    for (int t = 0; t < S_LEN / 64; ++t) {
        const int cur = t & 1;
        if (t + 1 < S_LEN / 64) STAGE_KV(!cur, (t + 1) * 64);   // prefetch in flight

        // S^T (this wave's 32 kv rows x 32 q cols), C init -12 (exp2 headroom)
        f32x16 sc;
        #pragma unroll
        for (int r = 0; r < 16; ++r) sc[r] = -12.f;
        __builtin_amdgcn_s_setprio(1);
        #pragma unroll
        for (int s = 0; s < 4; ++s) {
            bf16x8 kf = *(const bf16x8*)&smem[KS_OFF(cur) + SWZ8(wk * 32 + l31, s * 2 + hh)];
            sc = __builtin_amdgcn_mfma_f32_32x32x16_bf16(kf, qf[s], sc, 0, 0, 0);
        }
        __builtin_amdgcn_s_setprio(0);

        // p = exp2(s); x[g] covers kv_local = 8g + 4hh + {0..3}
        // v_cvt_pk_bf16_f32: 1 instr packs 2 f32 -> 2 bf16 (no builtin; asm)
        unsigned x[4][2];
        #pragma unroll
        for (int g = 0; g < 4; ++g) {
            float p0 = __builtin_amdgcn_exp2f(sc[4 * g + 0]);
            float p1 = __builtin_amdgcn_exp2f(sc[4 * g + 1]);
            float p2 = __builtin_amdgcn_exp2f(sc[4 * g + 2]);
            float p3 = __builtin_amdgcn_exp2f(sc[4 * g + 3]);
            l += (p0 + p1) + (p2 + p3);
            asm("v_cvt_pk_bf16_f32 %0, %1, %2" : "=v"(x[g][0]) : "v"(p0), "v"(p1));
            asm("v_cvt_pk_bf16_f32 %0, %1, %2" : "=v"(x[g][1]) : "v"(p2), "v"(p3));
        }

        // PV: B-frag(sp) covers kv_local = 16sp + 8hh + j.
        // pf.u[w] needs {lo lanes: x[ge][w&1].row0, hi lanes: x[go][w&1].row0}
        // (w<2) and row1 halves (w>=2) — exactly the two outputs of one
        // v_permlane32_swap_b32 (swaps row1(a) <-> row0(b)).
        #pragma unroll
        for (int sp = 0; sp < 2; ++sp) {
            unsigned a0 = x[2 * sp][0], b0 = x[2 * sp + 1][0];
            unsigned a1 = x[2 * sp][1], b1 = x[2 * sp + 1][1];
            asm("v_permlane32_swap_b32 %0, %1" : "+v"(a0), "+v"(b0));
            asm("v_permlane32_swap_b32 %0, %1" : "+v"(a1), "+v"(b1));
            union { unsigned u[4]; bf16x8 v; } pf;
            pf.u[0] = a0; pf.u[1] = a1; pf.u[2] = b0; pf.u[3] = b1;
            __builtin_amdgcn_s_setprio(1);
            #pragma unroll
            for (int dt = 0; dt < 2; ++dt) {
                bf16x8 vf = *(const bf16x8*)&smem[VS_OFF(cur) + SWZ8(dt * 32 + l31, wk * 4 + sp * 2 + hh)];
                o[dt] = __builtin_amdgcn_mfma_f32_32x32x16_bf16(vf, pf.v, o[dt], 0, 0, 0);
            }
            __builtin_amdgcn_s_setprio(0);
        }

        __syncthreads();   // drains prefetch + protects both staging buffers
    }

    // merge lane halves of l (each covers complementary kv groups)
    l += __shfl_xor(l, 32);

    // cross kv-half reduction through LDS (staging region is dead now)
    float* Ored = (float*)smem;                   // [4 qt][32 q][68] f32
    float* Lred = (float*)(smem + 17408);         // [4 qt][32 q] f32
    float* op = Ored + ((size_t)wq * 32 + l31) * 68;
    if (wk == 1) {
        #pragma unroll
        for (int dt = 0; dt < 2; ++dt)
            #pragma unroll
            for (int g = 0; g < 4; ++g)
                *(f32x4*)(op + dt * 32 + 8 * g + 4 * hh) =
                    (f32x4){o[dt][4 * g + 0], o[dt][4 * g + 1], o[dt][4 * g + 2], o[dt][4 * g + 3]};
        if (hh == 0) Lred[wq * 32 + l31] = l;
    }
    __syncthreads();
    if (wk == 0) {
        l += Lred[wq * 32 + l31];
        float inv = 1.0f / l;
        size_t orow = (qrow0 + wq * 32 + l31) * D_MODEL + colbase;
        #pragma unroll
        for (int dt = 0; dt < 2; ++dt)
            #pragma unroll
            for (int g = 0; g < 4; ++g) {
                f32x4 add = *(const f32x4*)(op + dt * 32 + 8 * g + 4 * hh);
                float v0 = (o[dt][4 * g + 0] + add[0]) * inv;
                float v1 = (o[dt][4 * g + 1] + add[1]) * inv;
                float v2 = (o[dt][4 * g + 2] + add[2]) * inv;
                float v3 = (o[dt][4 * g + 3] + add[3]) * inv;
                *(u32x2*)(aw + orow + dt * 32 + 8 * g + 4 * hh) =
                    (u32x2){pack2bf(v0, v1), pack2bf(v2, v3)};
            }
    }
    #undef STAGE_KV
    #undef KS_OFF
    #undef VS_OFF
}

// ---------------------------------------------------------------------------
// outproj: out[tok][dm] = aw @ Wo^T + bo (fp32 out). R5 rewrite with the
// proven R2-proj schedule: 128(dout) x 128(tok) tile -> 256 blocks (1/CU),
// 512 threads / 8 waves (2M x 4N), 32x32x16 MFMA, double-buffered LDS
// (64 KB), one vmcnt(0)+s_barrier per K-tile with next tile's 4
// global_load_lds issued right after the barrier (loads fly across the
// whole compute section). XCD-chunked: 32 consecutive works/XCD cover all
// 8 m-tiles (full 2 MB Wo panel) x 4 n-tiles (1 MB aw panel) -> L2-resident.
// Operand-swapped: A = Wo (m = dout), B = aw (n = token).
// ---------------------------------------------------------------------------
__global__ __launch_bounds__(512, 2) void outproj_kernel(
    const u16* __restrict__ aw, const u16* __restrict__ Wob,
    const float* __restrict__ bo, float* __restrict__ out)
{
    const int bid = blockIdx.x;               // 256 blocks
    const int wid = (bid & 7) * 32 + (bid >> 3);
    const int mbase = (wid & 7) * 128;        // dout  (8 m-tiles)
    const int nbase = (wid >> 3) * 128;       // token (32 n-tiles)

    const int tid = threadIdx.x, lane = tid & 63, wave = tid >> 6;
    const int l31 = lane & 31, hh = lane >> 5;
    const int wm = wave >> 2;        // 0..1 -> 64 dout rows
    const int wn = wave & 3;         // 0..3 -> 32 tokens

    // LDS u16 units: A[2][128*64] at 0, B[2][128*64] at 16384. 64 KB total.
    __shared__ __align__(16) u16 smem[32768];

    // staging: 1024 16B-chunks per 128x64 tile; thread owns chunks
    // p = c*512 + tid, c in {0,1}. row = p>>3, cg = (p&7)^(row&7).
    size_t aoff[2], boff[2];
    #pragma unroll
    for (int c = 0; c < 2; ++c) {
        int p = c * 512 + tid;
        int row = p >> 3;
        int cg  = (p & 7) ^ (row & 7);
        aoff[c] = (size_t)(mbase + row) * D_MODEL + cg * 8;
        boff[c] = (size_t)(nbase + row) * D_MODEL + cg * 8;
    }

#define OSTAGE(buf, kc)                                                             \
    do {                                                                            \
        _Pragma("unroll")                                                           \
        for (int c = 0; c < 2; ++c) {                                               \
            __builtin_amdgcn_global_load_lds(GAS(Wob + aoff[c] + (kc)),             \
                LAS(smem + (buf) * 8192 + c * 4096 + wave * 512), 16, 0, 0);        \
            __builtin_amdgcn_global_load_lds(GAS(aw + boff[c] + (kc)),              \
                LAS(smem + 16384 + (buf) * 8192 + c * 4096 + wave * 512), 16, 0, 0);\
        }                                                                           \
    } while (0)

    OSTAGE(0, 0);

    f32x16 acc[2];
    #pragma unroll
    for (int mt = 0; mt < 2; ++mt)
        #pragma unroll
        for (int q = 0; q < 16; ++q) acc[mt][q] = 0.f;

    for (int t = 0; t < D_MODEL / 64; ++t) {
        const int cur = t & 1;
        asm volatile("s_waitcnt vmcnt(0) lgkmcnt(0)" ::: "memory");
        __builtin_amdgcn_s_barrier();
        asm volatile("" ::: "memory");
        if (t < D_MODEL / 64 - 1) OSTAGE(cur ^ 1, (t + 1) * 64);
        const u16* Ab = smem + cur * 8192;
        const u16* Bb = smem + 16384 + cur * 8192;
        #pragma unroll
        for (int kk = 0; kk < 4; ++kk) {
            bf16x8 af[2], bfr;
            #pragma unroll
            for (int mt = 0; mt < 2; ++mt)
                af[mt] = *(const bf16x8*)&Ab[SWZ8(wm * 64 + mt * 32 + l31, kk * 2 + hh)];
            bfr = *(const bf16x8*)&Bb[SWZ8(wn * 32 + l31, kk * 2 + hh)];
            __builtin_amdgcn_s_setprio(1);
            #pragma unroll
            for (int mt = 0; mt < 2; ++mt)
                acc[mt] = __builtin_amdgcn_mfma_f32_32x32x16_bf16(af[mt], bfr, acc[mt], 0, 0, 0);
            __builtin_amdgcn_s_setprio(0);
        }
    }
#undef OSTAGE

    // C layout (32x32x16): col(token) = lane&31, row(dout) = (reg&3)+8*(reg>>2)+4*hh
    const int tok = nbase + wn * 32 + l31;
    float* orow = out + (size_t)tok * D_MODEL;
    #pragma unroll
    for (int mt = 0; mt < 2; ++mt)
        #pragma unroll
        for (int g = 0; g < 4; ++g) {
            const int d0 = mbase + wm * 64 + mt * 32 + 8 * g + 4 * hh;
            float4 b4 = *(const float4*)&bo[d0];
            float4 st;
            st.x = acc[mt][4 * g + 0] + b4.x;
            st.y = acc[mt][4 * g + 1] + b4.y;
            st.z = acc[mt][4 * g + 2] + b4.z;
            st.w = acc[mt][4 * g + 3] + b4.w;
            *(float4*)(orow + d0) = st;
        }
}

extern "C" void kernel_launch(void* const* d_in, const int* in_sizes, int n_in,
                              void* d_out, int out_size, void* d_ws, size_t ws_size,
                              hipStream_t stream) {
    const float* Q  = (const float*)d_in[0];
    const float* K  = (const float*)d_in[1];
    const float* V  = (const float*)d_in[2];
    const float* Wq = (const float*)d_in[3];
    const float* bq = (const float*)d_in[4];
    const float* Wk = (const float*)d_in[5];
    const float* bk = (const float*)d_in[6];
    const float* Wv = (const float*)d_in[7];
    const float* bv = (const float*)d_in[8];
    const float* Wo = (const float*)d_in[9];
    const float* bo = (const float*)d_in[10];

    const size_t NT = (size_t)NTOK * D_MODEL;    // 4M
    const size_t WN = (size_t)D_MODEL * D_MODEL; // 1M
    u16* base = (u16*)d_ws;                      // 28M u16 = 56 MB total
    u16* qw  = base;
    u16* kw  = base + NT;
    u16* vtw = base + 2 * NT;   // [1024 dout][4096 tok]
    u16* Qb  = base + 3 * NT;   // aliased by aww after proj
    u16* Kb  = base + 4 * NT;
    u16* Vb  = base + 5 * NT;
    u16* Wqb = base + 6 * NT;
    u16* Wkb = Wqb + WN;
    u16* Wvb = Wkb + WN;
    u16* Wob = Wvb + WN;
    u16* aww = Qb;              // Qb dead after proj

    convert_kernel<<<1024, 256, 0, stream>>>(Q, K, V, Wq, Wk, Wv, Wo,
                                             Qb, Kb, Vb, Wqb, Wkb, Wvb, Wob);
    proj_kernel<<<dim3(192), 512, 0, stream>>>(Qb, Kb, Vb, Wqb, Wkb, Wvb,
                                               bq, bk, bv, qw, kw, vtw);
    attn_kernel<<<dim3(S_LEN / 128, NHEAD, BATCH), 512, 0, stream>>>(qw, kw, vtw, aww);
    outproj_kernel<<<dim3(256), 512, 0, stream>>>(aww, Wob, bo, (float*)d_out);
}